// Round 1
// baseline (1103.729 us; speedup 1.0000x reference)
//
#include <hip/hip_runtime.h>
#include <hip/hip_bf16.h>

#define NR 8192
#define EDIM 128
#define WF 128
#define BM 32
#define BK 64
#define MSTR 131   // u64 stride for mask words (conflict-break)
#define HSTR 72    // ushort stride for bf16 LDS tiles (16B-aligned rows, bank spread)

typedef short bf16x8 __attribute__((ext_vector_type(8)));
typedef float f32x4 __attribute__((ext_vector_type(4)));

static __device__ __forceinline__ unsigned int f2bf(float f) {
    // RNE float->bf16 (finite inputs only here)
    unsigned int u = __float_as_uint(f);
    return (u + 0x7fffu + ((u >> 16) & 1u)) >> 16;
}

static __device__ __forceinline__ void atomicMaxF(float* addr, float v) {
    if (v >= 0.f) atomicMax((int*)addr, __float_as_int(v));
    else          atomicMin((unsigned int*)addr, __float_as_uint(v));
}

// ---------------- Kernel 1: h = emb[inSen] @ W ; f_src/f_dst ; hT (bf16, transposed) ----
__global__ __launch_bounds__(128) void k_proj(
    const int* __restrict__ inSen, const float* __restrict__ emb,
    const float* __restrict__ W, const float* __restrict__ a_src,
    const float* __restrict__ a_dst, float* __restrict__ f_src,
    float* __restrict__ f_dst, unsigned short* __restrict__ hT)
{
    __shared__ float WT[128 * 132];   // W transposed: WT[j][k]
    __shared__ float ht[32 * 132];    // h tile [row][feature]
    const int t = threadIdx.x;
    const int i0 = blockIdx.x * BM;

    for (int k = 0; k < EDIM; ++k) WT[t * 132 + k] = W[k * WF + t];  // own column, no barrier needed

    int wd[32];
    #pragma unroll
    for (int r = 0; r < BM; ++r) wd[r] = inSen[i0 + r];   // uniform -> SGPRs

    float h[32];
    #pragma unroll
    for (int r = 0; r < BM; ++r) h[r] = 0.f;

    const float4* Wt4 = (const float4*)(WT + t * 132);
    for (int k4 = 0; k4 < 32; ++k4) {
        float4 wc = Wt4[k4];
        #pragma unroll
        for (int r = 0; r < BM; ++r) {
            float4 ev = ((const float4*)(emb + (long)wd[r] * EDIM))[k4];  // uniform load
            h[r] += ev.x * wc.x + ev.y * wc.y + ev.z * wc.z + ev.w * wc.w;
        }
    }
    #pragma unroll
    for (int r = 0; r < BM; ++r) ht[r * 132 + t] = h[r];
    __syncthreads();

    if (t < BM) {
        float s = 0.f, d = 0.f;
        for (int k4 = 0; k4 < 32; ++k4) {
            float4 hv = *(const float4*)(ht + t * 132 + k4 * 4);
            float4 as = ((const float4*)a_src)[k4];
            float4 ad = ((const float4*)a_dst)[k4];
            s += hv.x * as.x + hv.y * as.y + hv.z * as.z + hv.w * as.w;
            d += hv.x * ad.x + hv.y * ad.y + hv.z * ad.z + hv.w * ad.w;
        }
        f_src[i0 + t] = s;
        f_dst[i0 + t] = d;
    }
    // transposed bf16 write: thread t = feature; 32 rows -> 4 x uint4
    #pragma unroll
    for (int q = 0; q < 4; ++q) {
        uint4 v;
        v.x = f2bf(ht[(q * 8 + 0) * 132 + t]) | (f2bf(ht[(q * 8 + 1) * 132 + t]) << 16);
        v.y = f2bf(ht[(q * 8 + 2) * 132 + t]) | (f2bf(ht[(q * 8 + 3) * 132 + t]) << 16);
        v.z = f2bf(ht[(q * 8 + 4) * 132 + t]) | (f2bf(ht[(q * 8 + 5) * 132 + t]) << 16);
        v.w = f2bf(ht[(q * 8 + 6) * 132 + t]) | (f2bf(ht[(q * 8 + 7) * 132 + t]) << 16);
        ((uint4*)(hT + (long)t * NR + i0))[q] = v;
    }
}

// ---------------- Kernel 1b: max(f_dst) + init pool to -inf ----------------------------
__global__ __launch_bounds__(256) void k_aux(
    const float* __restrict__ f_dst, float* __restrict__ maxfd, float* __restrict__ pool)
{
    __shared__ float s[256];
    const int t = threadIdx.x;
    float m = -1e30f;
    for (int j = t; j < NR; j += 256) m = fmaxf(m, f_dst[j]);
    s[t] = m;
    __syncthreads();
    for (int o = 128; o > 0; o >>= 1) {
        if (t < o) s[t] = fmaxf(s[t], s[t + o]);
        __syncthreads();
    }
    if (t == 0) maxfd[0] = s[0];
    if (t < WF) pool[t] = -INFINITY;
}

// ---------------- Kernel 2: fused mask/softmax/attention-write + MFMA PV ---------------
__global__ __launch_bounds__(256, 2) void k_main(
    const int* __restrict__ adj, const int* __restrict__ selfLinkP,
    const float* __restrict__ f_src, const float* __restrict__ f_dst,
    const float* __restrict__ maxfd, const unsigned short* __restrict__ hT,
    float* __restrict__ att, float* __restrict__ sent, float* __restrict__ pool)
{
    __shared__ unsigned long long maskL[BM * MSTR];            // 33.5 KB adj bitmask
    __shared__ __align__(16) unsigned short HTl[WF * HSTR];    // 18 KB  B tile (h^T)
    __shared__ __align__(16) unsigned short Pl[BM * HSTR];     // 4.5 KB A tile (p)
    __shared__ float fsl[BM], Cl[BM], invl[BM];
    __shared__ float sums[4][BM];

    const int t = threadIdx.x;
    const int lane = t & 63, w = t >> 6;
    const int i0 = blockIdx.x * BM;
    const int sl = selfLinkP[0];

    if (t < BM) {
        float fs = f_src[i0 + t];
        float c = fs + maxfd[0];
        c = c > 0.f ? c : 0.01f * c;     // lrelu(fs + max f_dst) >= every row score
        fsl[t] = fs;
        Cl[t] = c;
    }
    __syncthreads();

    // ---- phase 1: row sums l_i + bitmask pack (reads adj once) ----
    float sum[BM];
    #pragma unroll
    for (int r = 0; r < BM; ++r) sum[r] = 0.f;

    for (int cb = 0; cb < NR / 256; ++cb) {
        const int col = cb * 256 + w * 64 + lane;
        const float fd = f_dst[col];
        unsigned long long myword = 0ull;
        #pragma unroll
        for (int r = 0; r < BM; ++r) {
            const int i = i0 + r;
            int a = adj[(long)i * NR + col];
            int mval = a + ((col == i) ? sl : 0);
            bool m = mval > 0;
            float e = fsl[r] + fd;
            e = e > 0.f ? e : 0.01f * e;
            float p = m ? __expf(e - Cl[r]) : 0.f;
            sum[r] += p;
            unsigned long long b = __ballot(m);
            if (lane == r) myword = b;
        }
        if (lane < BM) maskL[lane * MSTR + cb * 4 + w] = myword;
    }
    #pragma unroll
    for (int r = 0; r < BM; ++r) {
        float v = sum[r];
        #pragma unroll
        for (int o = 1; o < 64; o <<= 1) v += __shfl_xor(v, o);
        if (lane == 0) sums[w][r] = v;
    }
    __syncthreads();
    if (t < BM) invl[t] = 1.0f / (sums[0][t] + sums[1][t] + sums[2][t] + sums[3][t]);
    __syncthreads();

    // ---- phase 2: attention write + MFMA accumulate sentence ----
    const int r2 = t >> 3, g = t & 7;           // p-compute mapping: 8 threads/row, 8 cols each
    const float fs2 = fsl[r2], C2 = Cl[r2], il2 = invl[r2];
    const int fx = lane & 15, quad = lane >> 4; // mfma lane decomposition
    const int n0 = w * 32;
    float* attRow = att + (long)i0 * NR + (long)r2 * NR;
    f32x4 acc[2][2] = {};

    for (int kk = 0; kk < NR; kk += BK) {
        // load B tile h^T[128][64] -> LDS
        #pragma unroll
        for (int rep = 0; rep < 4; ++rep) {
            const int f = rep * 32 + r2;
            float4 v = *(const float4*)(hT + (long)f * NR + kk + g * 8);
            *(float4*)(HTl + f * HSTR + g * 8) = v;
        }
        // compute p for 8 cols, write normalized attention, stash bf16 p
        const unsigned long long mw = maskL[r2 * MSTR + (kk >> 6)];
        const int cb8 = g * 8;
        float4 fd1 = *(const float4*)(f_dst + kk + cb8);
        float4 fd2 = *(const float4*)(f_dst + kk + cb8 + 4);
        auto pcalc = [&](float fd, int c) {
            float e = fs2 + fd;
            e = e > 0.f ? e : 0.01f * e;
            return ((mw >> c) & 1ull) ? __expf(e - C2) : 0.f;
        };
        float p0 = pcalc(fd1.x, cb8 + 0), p1 = pcalc(fd1.y, cb8 + 1);
        float p2 = pcalc(fd1.z, cb8 + 2), p3 = pcalc(fd1.w, cb8 + 3);
        float p4 = pcalc(fd2.x, cb8 + 4), p5 = pcalc(fd2.y, cb8 + 5);
        float p6 = pcalc(fd2.z, cb8 + 6), p7 = pcalc(fd2.w, cb8 + 7);
        float4 a0 = make_float4(p0 * il2, p1 * il2, p2 * il2, p3 * il2);
        float4 a1 = make_float4(p4 * il2, p5 * il2, p6 * il2, p7 * il2);
        *(float4*)(attRow + kk + cb8) = a0;
        *(float4*)(attRow + kk + cb8 + 4) = a1;
        uint4 pb;
        pb.x = f2bf(p0) | (f2bf(p1) << 16);
        pb.y = f2bf(p2) | (f2bf(p3) << 16);
        pb.z = f2bf(p4) | (f2bf(p5) << 16);
        pb.w = f2bf(p6) | (f2bf(p7) << 16);
        *(uint4*)(Pl + r2 * HSTR + cb8) = pb;
        __syncthreads();

        #pragma unroll
        for (int ks = 0; ks < 2; ++ks) {
            const int ko = ks * 32 + quad * 8;
            bf16x8 af0 = *(const bf16x8*)(Pl + fx * HSTR + ko);
            bf16x8 af1 = *(const bf16x8*)(Pl + (fx + 16) * HSTR + ko);
            bf16x8 bf0 = *(const bf16x8*)(HTl + (n0 + fx) * HSTR + ko);
            bf16x8 bf1 = *(const bf16x8*)(HTl + (n0 + 16 + fx) * HSTR + ko);
            acc[0][0] = __builtin_amdgcn_mfma_f32_16x16x32_bf16(af0, bf0, acc[0][0], 0, 0, 0);
            acc[0][1] = __builtin_amdgcn_mfma_f32_16x16x32_bf16(af0, bf1, acc[0][1], 0, 0, 0);
            acc[1][0] = __builtin_amdgcn_mfma_f32_16x16x32_bf16(af1, bf0, acc[1][0], 0, 0, 0);
            acc[1][1] = __builtin_amdgcn_mfma_f32_16x16x32_bf16(af1, bf1, acc[1][1], 0, 0, 0);
        }
        __syncthreads();
    }

    // epilogue: sentence = acc/l ; block-local colmax -> global atomic pool max
    #pragma unroll
    for (int nt = 0; nt < 2; ++nt) {
        float colmax = -1e30f;
        #pragma unroll
        for (int mt = 0; mt < 2; ++mt) {
            #pragma unroll
            for (int reg = 0; reg < 4; ++reg) {
                const int r = mt * 16 + quad * 4 + reg;
                float v = acc[mt][nt][reg] * invl[r];
                sent[(long)(i0 + r) * WF + n0 + nt * 16 + fx] = v;
                colmax = fmaxf(colmax, v);
            }
        }
        colmax = fmaxf(colmax, __shfl_xor(colmax, 16));
        colmax = fmaxf(colmax, __shfl_xor(colmax, 32));
        if (lane < 16) atomicMaxF(pool + n0 + nt * 16 + lane, colmax);
    }
}

// ---------------- Kernel 3: label = softmax(pool @ cls_W + cls_b) ----------------------
__global__ __launch_bounds__(128) void k_label(
    const float* __restrict__ pool, const float* __restrict__ cls_W,
    const float* __restrict__ cls_b, float* __restrict__ label)
{
    __shared__ float s0[128], s1[128];
    const int t = threadIdx.x;
    float v = pool[t];
    s0[t] = v * cls_W[t * 2 + 0];
    s1[t] = v * cls_W[t * 2 + 1];
    __syncthreads();
    if (t == 0) {
        float z0 = cls_b[0], z1 = cls_b[1];
        for (int f = 0; f < 128; ++f) { z0 += s0[f]; z1 += s1[f]; }
        float m = fmaxf(z0, z1);
        float e0 = __expf(z0 - m), e1 = __expf(z1 - m);
        float inv = 1.0f / (e0 + e1);
        label[0] = e0 * inv;
        label[1] = e1 * inv;
    }
}

extern "C" void kernel_launch(void* const* d_in, const int* in_sizes, int n_in,
                              void* d_out, int out_size, void* d_ws, size_t ws_size,
                              hipStream_t stream)
{
    const int*   inSen    = (const int*)d_in[0];
    const int*   adj      = (const int*)d_in[1];
    const int*   selfLink = (const int*)d_in[2];
    const float* emb      = (const float*)d_in[3];
    const float* W        = (const float*)d_in[4];
    const float* a_src    = (const float*)d_in[5];
    const float* a_dst    = (const float*)d_in[6];
    const float* cls_W    = (const float*)d_in[7];
    const float* cls_b    = (const float*)d_in[8];

    float* out   = (float*)d_out;
    float* pool  = out;                         // 128
    float* att   = out + 128;                   // 8192*8192
    float* sent  = att + (long)NR * NR;         // 8192*128
    float* label = sent + (long)NR * WF;        // 2

    char* ws = (char*)d_ws;
    unsigned short* hT = (unsigned short*)ws;            // 128*8192 bf16 = 2 MB
    float* f_src = (float*)(ws + (size_t)WF * NR * 2);
    float* f_dst = f_src + NR;
    float* maxfd = f_dst + NR;

    k_proj<<<NR / BM, 128, 0, stream>>>(inSen, emb, W, a_src, a_dst, f_src, f_dst, hT);
    k_aux<<<1, 256, 0, stream>>>(f_dst, maxfd, pool);
    k_main<<<NR / BM, 256, 0, stream>>>(adj, selfLink, f_src, f_dst, maxfd, hT, att, sent, pool);
    k_label<<<1, 128, 0, stream>>>(pool, cls_W, cls_b, label);
}

// Round 2
// 749.058 us; speedup vs baseline: 1.4735x; 1.4735x over previous
//
#include <hip/hip_runtime.h>
#include <hip/hip_bf16.h>

#define NR 8192
#define WF 128

typedef short bf16x8 __attribute__((ext_vector_type(8)));
typedef float f32x4 __attribute__((ext_vector_type(4)));

static __device__ __forceinline__ unsigned int f2bf(float f) {
    unsigned int u = __float_as_uint(f);
    return (u + 0x7fffu + ((u >> 16) & 1u)) >> 16;
}
static __device__ __forceinline__ void atomicMaxF(float* addr, float v) {
    if (v >= 0.f) atomicMax((int*)addr, __float_as_int(v));
    else          atomicMin((unsigned int*)addr, __float_as_uint(v));
}
static __device__ __forceinline__ float lrelu(float x) { return x > 0.f ? x : 0.01f * x; }

// ---- k_proj: h = emb[inSen] @ W ; f_src/f_dst ; hB (bf16, MFMA-B-fragment-linear) ----
// hB layout: [wordblk wb (256)][featgrp nf (8)][lane (64)][8 bf16]
//   lane = fx + 16*quad holds h^T[nf*16+fx][wb*32 + quad*8 + j], j=0..7  (1KB per frag)
__global__ __launch_bounds__(256) void k_proj(
    const int* __restrict__ inSen, const float* __restrict__ emb,
    const float* __restrict__ W, const float* __restrict__ a_src,
    const float* __restrict__ a_dst, float* __restrict__ f_src,
    float* __restrict__ f_dst, unsigned short* __restrict__ hB)
{
    __shared__ float ht[32 * 132];
    const int t = threadIdx.x;
    const int f = t & 127, rh = t >> 7;     // feature, row-half
    const int i0 = blockIdx.x * 32;

    int wd[16];
    #pragma unroll
    for (int r = 0; r < 16; ++r) wd[r] = inSen[i0 + rh * 16 + r];
    float h[16];
    #pragma unroll
    for (int r = 0; r < 16; ++r) h[r] = 0.f;

    for (int k4 = 0; k4 < 32; ++k4) {
        const float w0 = W[(k4 * 4 + 0) * WF + f];   // coalesced, L2-hot (64 KB)
        const float w1 = W[(k4 * 4 + 1) * WF + f];
        const float w2 = W[(k4 * 4 + 2) * WF + f];
        const float w3 = W[(k4 * 4 + 3) * WF + f];
        #pragma unroll
        for (int r = 0; r < 16; ++r) {
            float4 ev = ((const float4*)(emb + (size_t)wd[r] * 128))[k4];  // uniform bcast
            h[r] += ev.x * w0 + ev.y * w1 + ev.z * w2 + ev.w * w3;
        }
    }
    #pragma unroll
    for (int r = 0; r < 16; ++r) ht[(rh * 16 + r) * 132 + f] = h[r];
    __syncthreads();

    if (t < 32) {
        float s = 0.f, d = 0.f;
        for (int k4 = 0; k4 < 32; ++k4) {
            float4 hv = *(const float4*)(ht + t * 132 + k4 * 4);
            float4 as = ((const float4*)a_src)[k4];
            float4 ad = ((const float4*)a_dst)[k4];
            s += hv.x * as.x + hv.y * as.y + hv.z * as.z + hv.w * as.w;
            d += hv.x * ad.x + hv.y * ad.y + hv.z * ad.z + hv.w * ad.w;
        }
        f_src[i0 + t] = s;
        f_dst[i0 + t] = d;
    }
    // write hB fragments for this word-block (wb = blockIdx.x): 8 KB, coalesced
    #pragma unroll
    for (int e2 = 0; e2 < 2; ++e2) {
        const int e = t * 2 + e2;
        const int nf = e >> 6, lane = e & 63;
        const int fx = lane & 15, quad = lane >> 4;
        const float* hp = ht + (quad * 8) * 132 + nf * 16 + fx;
        uint4 v;
        v.x = f2bf(hp[0 * 132]) | (f2bf(hp[1 * 132]) << 16);
        v.y = f2bf(hp[2 * 132]) | (f2bf(hp[3 * 132]) << 16);
        v.z = f2bf(hp[4 * 132]) | (f2bf(hp[5 * 132]) << 16);
        v.w = f2bf(hp[6 * 132]) | (f2bf(hp[7 * 132]) << 16);
        *(uint4*)(hB + ((size_t)blockIdx.x * 8 + nf) * 512 + lane * 8) = v;
    }
}

// ---- k_aux: maxfd = max(f_dst) ; pool init to -inf ------------------------------------
__global__ __launch_bounds__(256) void k_aux(
    const float* __restrict__ f_dst, float* __restrict__ maxfd, float* __restrict__ pool)
{
    __shared__ float s[256];
    const int t = threadIdx.x;
    float m = -1e30f;
    for (int j = t; j < NR; j += 256) m = fmaxf(m, f_dst[j]);
    s[t] = m;
    __syncthreads();
    for (int o = 128; o > 0; o >>= 1) {
        if (t < o) s[t] = fmaxf(s[t], s[t + o]);
        __syncthreads();
    }
    if (t == 0) maxfd[0] = s[0];
    if (t < WF) pool[t] = -INFINITY;
}

// ---- k_adj: one block per row; pack mask bits + exp row-sum (reads adj once) ----------
__global__ __launch_bounds__(256) void k_adj(
    const int* __restrict__ adj, const int* __restrict__ slP,
    const float* __restrict__ f_src, const float* __restrict__ f_dst,
    const float* __restrict__ maxfd, unsigned int* __restrict__ maskG,
    float* __restrict__ invl)
{
    const int row = blockIdx.x;
    const int t = threadIdx.x;
    const int sl = slP[0];
    const float fs = f_src[row];
    const float C = lrelu(fs + maxfd[0]);   // >= every masked score of this row
    const int c0 = t * 32;
    const int4* ap = (const int4*)(adj + (size_t)row * NR + c0);
    unsigned int mw = 0;
    float sum = 0.f;
    #pragma unroll
    for (int q = 0; q < 8; ++q) {
        const int4 a = ap[q];
        const int cb = c0 + q * 4;
        const float4 fd = *(const float4*)(f_dst + cb);
        const int av[4] = {a.x, a.y, a.z, a.w};
        const float fv[4] = {fd.x, fd.y, fd.z, fd.w};
        #pragma unroll
        for (int j = 0; j < 4; ++j) {
            const bool m = (av[j] + (((cb + j) == row) ? sl : 0)) > 0;
            const float p = m ? __expf(lrelu(fs + fv[j]) - C) : 0.f;
            sum += p;
            mw |= m ? (1u << (q * 4 + j)) : 0u;
        }
    }
    maskG[(size_t)row * 256 + t] = mw;
    #pragma unroll
    for (int o = 1; o < 64; o <<= 1) sum += __shfl_xor(sum, o);
    __shared__ float ps[4];
    if ((t & 63) == 0) ps[t >> 6] = sum;
    __syncthreads();
    if (t == 0) invl[row] = 1.0f / (ps[0] + ps[1] + ps[2] + ps[3]);
}

// ---- k_att: barrier-free. wave = 16 rows x 1024-col K-split. p in A-frag layout, ------
// B-frags from hB (global, L2-resident), att streamed out, sentence via atomicAdd.
__global__ __launch_bounds__(256, 4) void k_att(
    const unsigned int* __restrict__ maskG, const float* __restrict__ f_src,
    const float* __restrict__ f_dst, const float* __restrict__ maxfd,
    const float* __restrict__ invl, const unsigned short* __restrict__ hB,
    float* __restrict__ att, float* __restrict__ sent)
{
    const int t = threadIdx.x;
    const int lane = t & 63;
    const int gw = blockIdx.x * 4 + (t >> 6);
    const int strip = gw >> 3, ks = gw & 7;   // 512 strips x 8 K-splits
    const int i0 = strip * 16;
    const int fx = lane & 15, quad = lane >> 4;
    const int row = i0 + fx;
    const float fs = f_src[row];
    const float C = lrelu(fs + maxfd[0]);
    const float il = invl[row];
    float* __restrict__ ar = att + (size_t)row * NR;
    const unsigned int* __restrict__ mrow = maskG + (size_t)row * 256;
    f32x4 acc[8] = {};
    const int k0 = ks * 1024;

    for (int kk = k0; kk < k0 + 1024; kk += 32) {
        const int kb = kk >> 5;
        const unsigned short* hp = hB + (size_t)kb * 4096 + lane * 8;
        bf16x8 bfr[8];
        #pragma unroll
        for (int nf = 0; nf < 8; ++nf) bfr[nf] = *(const bf16x8*)(hp + nf * 512);

        const unsigned int mbyte = (mrow[kb] >> (quad * 8)) & 0xffu;
        const float4 fd0 = *(const float4*)(f_dst + kk + quad * 8);
        const float4 fd1 = *(const float4*)(f_dst + kk + quad * 8 + 4);
        const float fv[8] = {fd0.x, fd0.y, fd0.z, fd0.w, fd1.x, fd1.y, fd1.z, fd1.w};
        float p[8];
        #pragma unroll
        for (int j = 0; j < 8; ++j)
            p[j] = ((mbyte >> j) & 1u) ? __expf(lrelu(fs + fv[j]) - C) : 0.f;

        // normalized attention out: quads of one row merge into a full 128B line
        const float4 w0 = make_float4(p[0] * il, p[1] * il, p[2] * il, p[3] * il);
        const float4 w1 = make_float4(p[4] * il, p[5] * il, p[6] * il, p[7] * il);
        *(float4*)(ar + kk + quad * 8) = w0;
        *(float4*)(ar + kk + quad * 8 + 4) = w1;

        union { uint4 u; bf16x8 v; } cv;
        cv.u.x = f2bf(p[0]) | (f2bf(p[1]) << 16);
        cv.u.y = f2bf(p[2]) | (f2bf(p[3]) << 16);
        cv.u.z = f2bf(p[4]) | (f2bf(p[5]) << 16);
        cv.u.w = f2bf(p[6]) | (f2bf(p[7]) << 16);
        #pragma unroll
        for (int nf = 0; nf < 8; ++nf)
            acc[nf] = __builtin_amdgcn_mfma_f32_16x16x32_bf16(cv.v, bfr[nf], acc[nf], 0, 0, 0);
    }
    // epilogue: D[m = quad*4+reg][n = nf*16+fx], normalize by row, accumulate
    #pragma unroll
    for (int reg = 0; reg < 4; ++reg) {
        const int m = quad * 4 + reg;
        const float vin = invl[i0 + m];
        #pragma unroll
        for (int nf = 0; nf < 8; ++nf)
            atomicAdd(&sent[(size_t)(i0 + m) * WF + nf * 16 + fx], acc[nf][reg] * vin);
    }
}

// ---- k_pool: column max over sent ------------------------------------------------------
__global__ __launch_bounds__(256) void k_pool(
    const float* __restrict__ sent, float* __restrict__ pool)
{
    __shared__ float s[256];
    const int t = threadIdx.x;
    const int f = t & 127, rh = t >> 7;
    const int r0 = blockIdx.x * 128;
    float m = -1e30f;
    for (int j = 0; j < 64; ++j)
        m = fmaxf(m, sent[(size_t)(r0 + j * 2 + rh) * WF + f]);
    s[t] = m;
    __syncthreads();
    if (t < 128) atomicMaxF(&pool[f], fmaxf(s[t], s[t + 128]));
}

// ---- k_label ---------------------------------------------------------------------------
__global__ __launch_bounds__(128) void k_label(
    const float* __restrict__ pool, const float* __restrict__ cls_W,
    const float* __restrict__ cls_b, float* __restrict__ label)
{
    __shared__ float s0[128], s1[128];
    const int t = threadIdx.x;
    float v = pool[t];
    s0[t] = v * cls_W[t * 2 + 0];
    s1[t] = v * cls_W[t * 2 + 1];
    __syncthreads();
    if (t == 0) {
        float z0 = cls_b[0], z1 = cls_b[1];
        for (int f = 0; f < 128; ++f) { z0 += s0[f]; z1 += s1[f]; }
        float m = fmaxf(z0, z1);
        float e0 = __expf(z0 - m), e1 = __expf(z1 - m);
        float inv = 1.0f / (e0 + e1);
        label[0] = e0 * inv;
        label[1] = e1 * inv;
    }
}

extern "C" void kernel_launch(void* const* d_in, const int* in_sizes, int n_in,
                              void* d_out, int out_size, void* d_ws, size_t ws_size,
                              hipStream_t stream)
{
    const int*   inSen    = (const int*)d_in[0];
    const int*   adj      = (const int*)d_in[1];
    const int*   selfLink = (const int*)d_in[2];
    const float* emb      = (const float*)d_in[3];
    const float* W        = (const float*)d_in[4];
    const float* a_src    = (const float*)d_in[5];
    const float* a_dst    = (const float*)d_in[6];
    const float* cls_W    = (const float*)d_in[7];
    const float* cls_b    = (const float*)d_in[8];

    float* out   = (float*)d_out;
    float* pool  = out;                         // 128
    float* att   = out + 128;                   // 8192*8192
    float* sent  = att + (size_t)NR * NR;       // 8192*128
    float* label = sent + (size_t)NR * WF;      // 2

    char* ws = (char*)d_ws;
    unsigned short* hB    = (unsigned short*)ws;               // 2 MB
    unsigned int*   maskG = (unsigned int*)(ws + (2u << 20));  // 8 MB
    float* f_src = (float*)(ws + (10u << 20));                 // 32 KB
    float* f_dst = f_src + NR;                                 // 32 KB
    float* invl  = f_dst + NR;                                 // 32 KB
    float* maxfd = invl + NR;                                  // 4 B

    hipMemsetAsync(sent, 0, (size_t)NR * WF * sizeof(float), stream);
    k_proj<<<NR / 32, 256, 0, stream>>>(inSen, emb, W, a_src, a_dst, f_src, f_dst, hB);
    k_aux<<<1, 256, 0, stream>>>(f_dst, maxfd, pool);
    k_adj<<<NR, 256, 0, stream>>>(adj, selfLink, f_src, f_dst, maxfd, maskG, invl);
    k_att<<<NR / 16 * 8 / 4, 256, 0, stream>>>(maskG, f_src, f_dst, maxfd, invl, hB, att, sent);
    k_pool<<<NR / 128, 256, 0, stream>>>(sent, pool);
    k_label<<<1, 128, 0, stream>>>(pool, cls_W, cls_b, label);
}

// Round 3
// 730.212 us; speedup vs baseline: 1.5115x; 1.0258x over previous
//
#include <hip/hip_runtime.h>
#include <hip/hip_bf16.h>

#define NR 8192
#define WF 128

typedef short bf16x8 __attribute__((ext_vector_type(8)));
typedef float f32x4 __attribute__((ext_vector_type(4)));

static __device__ __forceinline__ unsigned int f2bf(float f) {
    unsigned int u = __float_as_uint(f);
    return (u + 0x7fffu + ((u >> 16) & 1u)) >> 16;
}
static __device__ __forceinline__ void atomicMaxF(float* addr, float v) {
    if (v >= 0.f) atomicMax((int*)addr, __float_as_int(v));
    else          atomicMin((unsigned int*)addr, __float_as_uint(v));
}
static __device__ __forceinline__ float lrelu(float x) { return x > 0.f ? x : 0.01f * x; }

// ---- k_proj: h = emb[inSen] @ W ; f_src/f_dst ; hB (bf16, MFMA-B-fragment-linear) ----
// hB layout: [colblk kb (256)][featgrp nf (8)][lane (64)][8 bf16]; lane = fx + 16*quad
// holds h^T[nf*16+fx][kb*32 + quad*8 + j], j=0..7.  Block = 16 rows (half a colblk).
__global__ __launch_bounds__(256) void k_proj(
    const int* __restrict__ inSen, const float* __restrict__ emb,
    const float* __restrict__ W, const float* __restrict__ a_src,
    const float* __restrict__ a_dst, float* __restrict__ f_src,
    float* __restrict__ f_dst, unsigned short* __restrict__ hB)
{
    __shared__ float ht[16 * 132];
    const int t = threadIdx.x;
    const int f = t & 127, rh = t >> 7;     // feature, row-half (8 rows each)
    const int i0 = blockIdx.x * 16;

    int wd[8];
    #pragma unroll
    for (int r = 0; r < 8; ++r) wd[r] = inSen[i0 + rh * 8 + r];
    float h[8];
    #pragma unroll
    for (int r = 0; r < 8; ++r) h[r] = 0.f;

    for (int k4 = 0; k4 < 32; ++k4) {
        const float w0 = W[(k4 * 4 + 0) * WF + f];
        const float w1 = W[(k4 * 4 + 1) * WF + f];
        const float w2 = W[(k4 * 4 + 2) * WF + f];
        const float w3 = W[(k4 * 4 + 3) * WF + f];
        #pragma unroll
        for (int r = 0; r < 8; ++r) {
            float4 ev = ((const float4*)(emb + (size_t)wd[r] * 128))[k4];
            h[r] += ev.x * w0 + ev.y * w1 + ev.z * w2 + ev.w * w3;
        }
    }
    #pragma unroll
    for (int r = 0; r < 8; ++r) ht[(rh * 8 + r) * 132 + f] = h[r];
    __syncthreads();

    if (t < 16) {
        float s = 0.f, d = 0.f;
        for (int k4 = 0; k4 < 32; ++k4) {
            float4 hv = *(const float4*)(ht + t * 132 + k4 * 4);
            float4 as = ((const float4*)a_src)[k4];
            float4 ad = ((const float4*)a_dst)[k4];
            s += hv.x * as.x + hv.y * as.y + hv.z * as.z + hv.w * as.w;
            d += hv.x * ad.x + hv.y * ad.y + hv.z * ad.z + hv.w * ad.w;
        }
        f_src[i0 + t] = s;
        f_dst[i0 + t] = d;
    }
    // hB fragment write: this block fills quads {half*2, half*2+1} of colblk kb
    {
        const int kb = blockIdx.x >> 1, half = blockIdx.x & 1;
        const int nf = t >> 5, l32 = t & 31;
        const int qloc = l32 >> 4, fx = l32 & 15;
        const int lane = (half * 2 + qloc) * 16 + fx;
        const float* hp = ht + (qloc * 8) * 132 + nf * 16 + fx;
        uint4 v;
        v.x = f2bf(hp[0 * 132]) | (f2bf(hp[1 * 132]) << 16);
        v.y = f2bf(hp[2 * 132]) | (f2bf(hp[3 * 132]) << 16);
        v.z = f2bf(hp[4 * 132]) | (f2bf(hp[5 * 132]) << 16);
        v.w = f2bf(hp[6 * 132]) | (f2bf(hp[7 * 132]) << 16);
        *(uint4*)(hB + ((size_t)kb * 8 + nf) * 512 + lane * 8) = v;
    }
}

// ---- k_aux: maxfd = max(f_dst) ; pool init to -inf ------------------------------------
__global__ __launch_bounds__(256) void k_aux(
    const float* __restrict__ f_dst, float* __restrict__ maxfd, float* __restrict__ pool)
{
    __shared__ float s[256];
    const int t = threadIdx.x;
    float m = -1e30f;
    for (int j = t; j < NR; j += 256) m = fmaxf(m, f_dst[j]);
    s[t] = m;
    __syncthreads();
    for (int o = 128; o > 0; o >>= 1) {
        if (t < o) s[t] = fmaxf(s[t], s[t + o]);
        __syncthreads();
    }
    if (t == 0) maxfd[0] = s[0];
    if (t < WF) pool[t] = -INFINITY;
}

// ---- k_adj: 8 rows/block. Coalesced adj dword stream, f_dst in LDS, ballot-native -----
// mask words (one ballot = 64 consecutive cols = one aligned u64 store from lane 0).
__global__ __launch_bounds__(256, 4) void k_adj(
    const int* __restrict__ adj, const int* __restrict__ slP,
    const float* __restrict__ f_src, const float* __restrict__ f_dst,
    const float* __restrict__ maxfd, unsigned int* __restrict__ maskG,
    float* __restrict__ invl)
{
    __shared__ float fdl[NR];
    __shared__ float psum[8][4];
    const int t = threadIdx.x, lane = t & 63, w = t >> 6;
    const int r0 = blockIdx.x * 8;

    #pragma unroll
    for (int i = 0; i < 8; ++i)
        *(float4*)(fdl + i * 1024 + t * 4) = *(const float4*)(f_dst + i * 1024 + t * 4);
    const int sl = slP[0];
    const float mfd = maxfd[0];
    __syncthreads();

    #pragma unroll 1
    for (int r = 0; r < 8; ++r) {
        const int row = r0 + r;
        const float fs = f_src[row];
        const float C = lrelu(fs + mfd);
        const int* arow = adj + (size_t)row * NR;
        unsigned int* mrow = maskG + (size_t)row * 256;
        float sum = 0.f;
        for (int ch = 0; ch < 8; ++ch) {
            const int base = ch * 1024;
            #pragma unroll
            for (int j = 0; j < 4; ++j) {
                const int col = base + j * 256 + t;
                const int a = arow[col];
                const bool m = (a + ((col == row) ? sl : 0)) > 0;
                const float p = m ? __expf(lrelu(fs + fdl[col]) - C) : 0.f;
                sum += p;
                const unsigned long long b = __ballot(m);
                if (lane == 0)
                    *(unsigned long long*)(mrow + ch * 32 + j * 8 + w * 2) = b;
            }
        }
        #pragma unroll
        for (int o = 1; o < 64; o <<= 1) sum += __shfl_xor(sum, o);
        if (lane == 0) psum[r][w] = sum;
    }
    __syncthreads();
    if (t < 8)
        invl[r0 + t] = 1.0f / (psum[t][0] + psum[t][1] + psum[t][2] + psum[t][3]);
}

// ---- k_att: barrier-free K-loop. wave = 16 rows x 1024-col K-split. p in A-frag -------
// layout, B-frags from hB (L2-resident), att streamed, sent via LDS-reduce + atomics.
__global__ __launch_bounds__(256, 4) void k_att(
    const unsigned int* __restrict__ maskG, const float* __restrict__ f_src,
    const float* __restrict__ f_dst, const float* __restrict__ maxfd,
    const float* __restrict__ invl, const unsigned short* __restrict__ hB,
    float* __restrict__ att, float* __restrict__ sent)
{
    __shared__ float red[4][2048];
    const int t = threadIdx.x;
    const int lane = t & 63, w = t >> 6;
    const int gw = blockIdx.x * 4 + w;
    const int strip = gw >> 3, ks = gw & 7;   // 512 strips x 8 K-splits; block = 1 strip
    const int i0 = strip * 16;
    const int fx = lane & 15, quad = lane >> 4;
    const int row = i0 + fx;
    const float fs = f_src[row];
    const float C = lrelu(fs + maxfd[0]);
    const float il = invl[row];
    float* __restrict__ ar = att + (size_t)row * NR;
    const unsigned int* __restrict__ mrow = maskG + (size_t)row * 256;
    f32x4 acc[8] = {};
    const int k0 = ks * 1024;

    for (int kk = k0; kk < k0 + 1024; kk += 32) {
        const int kb = kk >> 5;
        const unsigned short* hp = hB + (size_t)kb * 4096 + lane * 8;
        bf16x8 bfr[8];
        #pragma unroll
        for (int nf = 0; nf < 8; ++nf) bfr[nf] = *(const bf16x8*)(hp + nf * 512);

        const unsigned int mbyte = (mrow[kb] >> (quad * 8)) & 0xffu;
        const float4 fd0 = *(const float4*)(f_dst + kk + quad * 8);
        const float4 fd1 = *(const float4*)(f_dst + kk + quad * 8 + 4);
        const float fv[8] = {fd0.x, fd0.y, fd0.z, fd0.w, fd1.x, fd1.y, fd1.z, fd1.w};
        float p[8];
        #pragma unroll
        for (int j = 0; j < 8; ++j)
            p[j] = ((mbyte >> j) & 1u) ? __expf(lrelu(fs + fv[j]) - C) : 0.f;

        const float4 w0 = make_float4(p[0] * il, p[1] * il, p[2] * il, p[3] * il);
        const float4 w1 = make_float4(p[4] * il, p[5] * il, p[6] * il, p[7] * il);
        *(float4*)(ar + kk + quad * 8) = w0;
        *(float4*)(ar + kk + quad * 8 + 4) = w1;

        union { uint4 u; bf16x8 v; } cv;
        cv.u.x = f2bf(p[0]) | (f2bf(p[1]) << 16);
        cv.u.y = f2bf(p[2]) | (f2bf(p[3]) << 16);
        cv.u.z = f2bf(p[4]) | (f2bf(p[5]) << 16);
        cv.u.w = f2bf(p[6]) | (f2bf(p[7]) << 16);
        #pragma unroll
        for (int nf = 0; nf < 8; ++nf)
            acc[nf] = __builtin_amdgcn_mfma_f32_16x16x32_bf16(cv.v, bfr[nf], acc[nf], 0, 0, 0);
    }
    // cross-wave reduce (block's 4 waves = same strip, different K-splits), then atomics
    #pragma unroll
    for (int reg = 0; reg < 4; ++reg) {
        #pragma unroll
        for (int nf = 0; nf < 8; ++nf)
            red[w][(quad * 4 + reg) * 128 + nf * 16 + fx] = acc[nf][reg];
    }
    __syncthreads();
    {
        const int e0 = t * 8;
        const int m = e0 >> 7, f0 = e0 & 127;
        const float vin = invl[i0 + m];
        float* sp = sent + (size_t)(i0 + m) * WF + f0;
        #pragma unroll
        for (int j = 0; j < 8; ++j) {
            const float v = red[0][e0 + j] + red[1][e0 + j] + red[2][e0 + j] + red[3][e0 + j];
            atomicAdd(sp + j, v * vin);
        }
    }
}

// ---- k_pool: column max over sent ------------------------------------------------------
__global__ __launch_bounds__(256) void k_pool(
    const float* __restrict__ sent, float* __restrict__ pool)
{
    __shared__ float s[256];
    const int t = threadIdx.x;
    const int f = t & 127, rh = t >> 7;
    const int r0 = blockIdx.x * 128;
    float m = -1e30f;
    for (int j = 0; j < 64; ++j)
        m = fmaxf(m, sent[(size_t)(r0 + j * 2 + rh) * WF + f]);
    s[t] = m;
    __syncthreads();
    if (t < 128) atomicMaxF(&pool[f], fmaxf(s[t], s[t + 128]));
}

// ---- k_label ---------------------------------------------------------------------------
__global__ __launch_bounds__(128) void k_label(
    const float* __restrict__ pool, const float* __restrict__ cls_W,
    const float* __restrict__ cls_b, float* __restrict__ label)
{
    __shared__ float s0[128], s1[128];
    const int t = threadIdx.x;
    float v = pool[t];
    s0[t] = v * cls_W[t * 2 + 0];
    s1[t] = v * cls_W[t * 2 + 1];
    __syncthreads();
    if (t == 0) {
        float z0 = cls_b[0], z1 = cls_b[1];
        for (int f = 0; f < 128; ++f) { z0 += s0[f]; z1 += s1[f]; }
        float m = fmaxf(z0, z1);
        float e0 = __expf(z0 - m), e1 = __expf(z1 - m);
        float inv = 1.0f / (e0 + e1);
        label[0] = e0 * inv;
        label[1] = e1 * inv;
    }
}

extern "C" void kernel_launch(void* const* d_in, const int* in_sizes, int n_in,
                              void* d_out, int out_size, void* d_ws, size_t ws_size,
                              hipStream_t stream)
{
    const int*   inSen    = (const int*)d_in[0];
    const int*   adj      = (const int*)d_in[1];
    const int*   selfLink = (const int*)d_in[2];
    const float* emb      = (const float*)d_in[3];
    const float* W        = (const float*)d_in[4];
    const float* a_src    = (const float*)d_in[5];
    const float* a_dst    = (const float*)d_in[6];
    const float* cls_W    = (const float*)d_in[7];
    const float* cls_b    = (const float*)d_in[8];

    float* out   = (float*)d_out;
    float* pool  = out;                         // 128
    float* att   = out + 128;                   // 8192*8192
    float* sent  = att + (size_t)NR * NR;       // 8192*128
    float* label = sent + (size_t)NR * WF;      // 2

    char* ws = (char*)d_ws;
    unsigned short* hB    = (unsigned short*)ws;               // 2 MB
    unsigned int*   maskG = (unsigned int*)(ws + (2u << 20));  // 8 MB
    float* f_src = (float*)(ws + (10u << 20));                 // 32 KB
    float* f_dst = f_src + NR;                                 // 32 KB
    float* invl  = f_dst + NR;                                 // 32 KB
    float* maxfd = invl + NR;                                  // 4 B

    hipMemsetAsync(sent, 0, (size_t)NR * WF * sizeof(float), stream);
    k_proj<<<NR / 16, 256, 0, stream>>>(inSen, emb, W, a_src, a_dst, f_src, f_dst, hB);
    k_aux<<<1, 256, 0, stream>>>(f_dst, maxfd, pool);
    k_adj<<<NR / 8, 256, 0, stream>>>(adj, selfLink, f_src, f_dst, maxfd, maskG, invl);
    k_att<<<NR / 16 * 8 / 4, 256, 0, stream>>>(maskG, f_src, f_dst, maxfd, invl, hB, att, sent);
    k_pool<<<NR / 128, 256, 0, stream>>>(sent, pool);
    k_label<<<1, 128, 0, stream>>>(pool, cls_W, cls_b, label);
}